// Round 6
// baseline (436.385 us; speedup 1.0000x reference)
//
#include <hip/hip_runtime.h>

using v8s = __attribute__((ext_vector_type(8))) short;          // 8 bf16 MFMA frag
using v4f = __attribute__((ext_vector_type(4))) float;          // MFMA acc
using v4u = __attribute__((ext_vector_type(4))) unsigned short; // 8B packed
using v8u = __attribute__((ext_vector_type(8))) unsigned short; // 16B copy

// fp32 -> bf16 RNE
__device__ __forceinline__ unsigned short f2b(float x) {
  unsigned int u = __builtin_bit_cast(unsigned int, x);
  return (unsigned short)((u + 0x7FFFu + ((u >> 16) & 1u)) >> 16);
}
// load 8 consecutive f32, convert to 8 bf16
__device__ __forceinline__ v8u cvt8(const float* p) {
  const float4 a = *(const float4*)p;
  const float4 b = *(const float4*)(p + 4);
  return (v8u){f2b(a.x), f2b(a.y), f2b(a.z), f2b(a.w),
               f2b(b.x), f2b(b.y), f2b(b.z), f2b(b.w)};
}

// ---------------------------------------------------------------------------
// GEMM: C[m,n] = sum_k A[m,k] * Bw[n,k]  (B^T weights, row-major, lda=ldb=K)
// 128x128 tile, BK=32, 256 threads (4 waves 2x2 of 64x64), 16x16x32 bf16 MFMA.
// AF/BF: operand is f32 (convert during staging) vs bf16. OF: output f32.
// mode 1 (QKV): cols<1536 -> Cb (bf16, ldc=1536); cols>=1536 (V third) stored
// TRANSPOSED into VT[(b*3+h)*256 + d][2048 tokens] (bf16).
// ---------------------------------------------------------------------------
template <bool AF, bool BF, bool OF>
__global__ __launch_bounds__(256, 2)
void gemm_bt_kernel(const void* __restrict__ Av, const void* __restrict__ Bv,
                    void* __restrict__ Cv, unsigned short* __restrict__ VT,
                    int K, int ldc, int mode) {
  __shared__ unsigned short As[4096];  // 128 x 32 bf16
  __shared__ unsigned short Bs[4096];

  const int t    = threadIdx.x;
  const int ln   = t & 63;
  const int wv   = t >> 6;
  const int quad = ln >> 4;
  const int L    = ln & 15;
  const int wm   = (wv >> 1) * 64;
  const int wn   = (wv & 1) * 64;
  const long m0  = (long)blockIdx.y * 128;
  const long n0  = (long)blockIdx.x * 128;

  v4f acc[4][4];
#pragma unroll
  for (int i = 0; i < 4; i++)
#pragma unroll
    for (int j = 0; j < 4; j++) acc[i][j] = (v4f){0.f, 0.f, 0.f, 0.f};

  const int ar = t >> 2;
  const int ac = (t & 3) * 8;
  const long offA = (m0 + ar) * (long)K + ac;
  const long offB = (n0 + ar) * (long)K + ac;
  const long rowskip = 64L * K;
  unsigned short* la = &As[ar * 32 + ac];
  unsigned short* lb = &Bs[ar * 32 + ac];

  const float* Af = (const float*)Av;
  const unsigned short* Ab = (const unsigned short*)Av;
  const float* Bf = (const float*)Bv;
  const unsigned short* Bb = (const unsigned short*)Bv;

  for (int k0 = 0; k0 < K; k0 += 32) {
    v8u a0, a1, b0, b1;
    if (AF) { a0 = cvt8(Af + offA + k0); a1 = cvt8(Af + offA + rowskip + k0); }
    else    { a0 = *(const v8u*)(Ab + offA + k0); a1 = *(const v8u*)(Ab + offA + rowskip + k0); }
    if (BF) { b0 = cvt8(Bf + offB + k0); b1 = cvt8(Bf + offB + rowskip + k0); }
    else    { b0 = *(const v8u*)(Bb + offB + k0); b1 = *(const v8u*)(Bb + offB + rowskip + k0); }
    __syncthreads();
    *(v8u*)la = a0;
    *(v8u*)(la + 2048) = a1;
    *(v8u*)lb = b0;
    *(v8u*)(lb + 2048) = b1;
    __syncthreads();

    v8s af[4], bfr[4];
#pragma unroll
    for (int i = 0; i < 4; i++)
      af[i] = *(const v8s*)(&As[(wm + i * 16 + L) * 32 + quad * 8]);
#pragma unroll
    for (int j = 0; j < 4; j++)
      bfr[j] = *(const v8s*)(&Bs[(wn + j * 16 + L) * 32 + quad * 8]);
#pragma unroll
    for (int i = 0; i < 4; i++)
#pragma unroll
      for (int j = 0; j < 4; j++)
        acc[i][j] = __builtin_amdgcn_mfma_f32_16x16x32_bf16(af[i], bfr[j], acc[i][j], 0, 0, 0);
  }

  // epilogue: C/D layout row = quad*4 + r, col = L (per 16x16 tile)
  if (mode == 0 || n0 < 1536) {
#pragma unroll
    for (int i = 0; i < 4; i++)
#pragma unroll
      for (int j = 0; j < 4; j++)
#pragma unroll
        for (int r = 0; r < 4; r++) {
          long row = m0 + wm + i * 16 + quad * 4 + r;
          long col = n0 + wn + j * 16 + L;
          if (OF) ((float*)Cv)[row * ldc + col] = acc[i][j][r];
          else    ((unsigned short*)Cv)[row * ldc + col] = f2b(acc[i][j][r]);
        }
  } else {
    // V region: write transposed VT[(b*3+h)*256 + d][token] (bf16)
#pragma unroll
    for (int i = 0; i < 4; i++)
#pragma unroll
      for (int j = 0; j < 4; j++) {
        int colp   = (int)(n0 + wn + j * 16 + L) - 1536;  // 0..767
        int h      = colp >> 8;
        int d      = colp & 255;
        long token = m0 + wm + i * 16 + quad * 4;  // 4-aligned; r -> consecutive tokens
        int b  = (int)(token >> 11);
        int tk = (int)(token & 2047);
        v4u val = {f2b(acc[i][j][0]), f2b(acc[i][j][1]), f2b(acc[i][j][2]), f2b(acc[i][j][3])};
        *(v4u*)(&VT[((long)(b * 3 + h) * 256 + d) * 2048 + tk]) = val;
      }
  }
}

// ---------------------------------------------------------------------------
// Flash attention, causal. One block = 64 q-rows of one (b,h); 4 waves x 16 rows.
// QK buf: [8192 tok][1536] bf16 (Q cols 0..767, K cols 768..1535), VT: [3072][2048].
// ---------------------------------------------------------------------------
__global__ __launch_bounds__(256, 2)
void attn_kernel(const unsigned short* __restrict__ QK,
                 const unsigned short* __restrict__ VT,
                 unsigned short* __restrict__ Out) {
  __shared__ unsigned short Ks[32 * 264];    // [key 32][d 256 + pad 8]
  __shared__ unsigned short VTs[256 * 40];   // [d 256][key 32 + pad 8]
  __shared__ unsigned short Ps[4 * 16 * 40]; // per-wave [q 16][key 32 + pad 8]

  const int t    = threadIdx.x;
  const int wv   = t >> 6;
  const int ln   = t & 63;
  const int quad = ln >> 4;
  const int L    = ln & 15;

  const int tile = 31 - (int)blockIdx.x;  // heavy tiles first
  const int bh   = (int)blockIdx.y;
  const int b    = bh / 3, h = bh % 3;
  const int qrow = tile * 64 + wv * 16;

  v8s qf[8];
  {
    const unsigned short* Qb =
        QK + (long)(b * 2048 + qrow + L) * 1536 + h * 256 + quad * 8;
#pragma unroll
    for (int kc = 0; kc < 8; kc++) qf[kc] = *(const v8s*)(Qb + kc * 32);
  }

  v4f o[16];
#pragma unroll
  for (int dt = 0; dt < 16; dt++) o[dt] = (v4f){0.f, 0.f, 0.f, 0.f};
  float mrow[4] = {-1e9f, -1e9f, -1e9f, -1e9f};
  float lrow[4] = {0.f, 0.f, 0.f, 0.f};

  const unsigned short* Kg = QK + (long)(b * 2048) * 1536 + 768 + h * 256;
  const unsigned short* Vg = VT + (long)bh * 256 * 2048;

  const int nkt = 2 * tile + 2;
  for (int kt = 0; kt < nkt; kt++) {
    __syncthreads();
#pragma unroll
    for (int p = 0; p < 4; p++) {
      int idx = p * 256 + t;
      int kn = idx >> 5, kc = idx & 31;
      *(v8u*)(&Ks[kn * 264 + kc * 8]) =
          *(const v8u*)(Kg + (long)(kt * 32 + kn) * 1536 + kc * 8);
      int d = idx >> 2, vc = idx & 3;
      *(v8u*)(&VTs[d * 40 + vc * 8]) =
          *(const v8u*)(Vg + (long)d * 2048 + kt * 32 + vc * 8);
    }
    __syncthreads();

    if (kt * 32 <= qrow) {  // wave-uniform causal guard
      v4f s0 = (v4f){0.f, 0.f, 0.f, 0.f}, s1 = s0;
#pragma unroll
      for (int kc = 0; kc < 8; kc++) {
        v8s kf0 = *(const v8s*)(&Ks[L * 264 + kc * 32 + quad * 8]);
        v8s kf1 = *(const v8s*)(&Ks[(16 + L) * 264 + kc * 32 + quad * 8]);
        s0 = __builtin_amdgcn_mfma_f32_16x16x32_bf16(qf[kc], kf0, s0, 0, 0, 0);
        s1 = __builtin_amdgcn_mfma_f32_16x16x32_bf16(qf[kc], kf1, s1, 0, 0, 0);
      }
      float al[4], p0[4], p1[4];
#pragma unroll
      for (int r = 0; r < 4; r++) {
        int row = qrow + quad * 4 + r;
        int c0  = kt * 32 + L;
        float v0 = (c0 <= row) ? s0[r] * 0.0625f : -1e9f;
        float v1 = (c0 + 16 <= row) ? s1[r] * 0.0625f : -1e9f;
        float mx = fmaxf(v0, v1);
        mx = fmaxf(mx, __shfl_xor(mx, 1));
        mx = fmaxf(mx, __shfl_xor(mx, 2));
        mx = fmaxf(mx, __shfl_xor(mx, 4));
        mx = fmaxf(mx, __shfl_xor(mx, 8));
        float mn = fmaxf(mrow[r], mx);
        float a  = __expf(mrow[r] - mn);
        float e0 = __expf(v0 - mn);
        float e1 = __expf(v1 - mn);
        float sm = e0 + e1;
        sm += __shfl_xor(sm, 1);
        sm += __shfl_xor(sm, 2);
        sm += __shfl_xor(sm, 4);
        sm += __shfl_xor(sm, 8);
        mrow[r] = mn;
        lrow[r] = lrow[r] * a + sm;
        al[r] = a; p0[r] = e0; p1[r] = e1;
      }
#pragma unroll
      for (int dt = 0; dt < 16; dt++)
#pragma unroll
        for (int r = 0; r < 4; r++) o[dt][r] *= al[r];
      // P: C-layout -> per-wave LDS -> A-layout
      unsigned short* Pw = &Ps[wv * 640 + (quad * 4) * 40 + L];
#pragma unroll
      for (int r = 0; r < 4; r++) {
        Pw[r * 40]      = f2b(p0[r]);
        Pw[r * 40 + 16] = f2b(p1[r]);
      }
      __threadfence_block();
      v8s pf = *(const v8s*)(&Ps[wv * 640 + L * 40 + quad * 8]);
#pragma unroll
      for (int dt = 0; dt < 16; dt++) {
        v8s vf = *(const v8s*)(&VTs[(dt * 16 + L) * 40 + quad * 8]);
        o[dt] = __builtin_amdgcn_mfma_f32_16x16x32_bf16(pf, vf, o[dt], 0, 0, 0);
      }
    }
  }

  float inv[4];
#pragma unroll
  for (int r = 0; r < 4; r++) inv[r] = 1.0f / fmaxf(lrow[r], 1e-20f);
#pragma unroll
  for (int dt = 0; dt < 16; dt++)
#pragma unroll
    for (int r = 0; r < 4; r++) {
      long row = (long)(b * 2048 + qrow + quad * 4 + r);
      Out[row * 768 + h * 256 + dt * 16 + L] = f2b(o[dt][r] * inv[r]);
    }
}

// ---------------------------------------------------------------------------
extern "C" void kernel_launch(void* const* d_in, const int* in_sizes, int n_in,
                              void* d_out, int out_size, void* d_ws, size_t ws_size,
                              hipStream_t stream) {
  // Inputs f32 (established R3-R5 bit-identity); OUTPUT f32 (R5 conclusion).
  const void* X     = d_in[0];  // [4,2048,768] f32
  const void* Wqkv  = d_in[1];  // [2304,768]   f32
  const void* Wproj = d_in[2];  // [768,768]    f32
  float* out = (float*)d_out;   // [4,2048,768] f32

  char* ws = (char*)d_ws;
  unsigned short* QKb = (unsigned short*)ws;                              // [8192][1536]  25.2 MB
  unsigned short* VTb = (unsigned short*)(ws + (size_t)8192 * 1536 * 2);  // [3072][2048]  12.6 MB
  unsigned short* AOb = (unsigned short*)(ws + (size_t)8192 * 1536 * 2 +
                                          (size_t)12 * 256 * 2048 * 2);   // [8192][768]   12.6 MB

  dim3 blk(256, 1, 1);
  // 1) QKV projection (f32 in, bf16 out; V stored transposed)
  gemm_bt_kernel<true, true, false><<<dim3(18, 64, 1), blk, 0, stream>>>(
      X, Wqkv, QKb, VTb, 768, 1536, 1);
  // 2) causal MFMA flash attention (bf16 workspace)
  attn_kernel<<<dim3(32, 12, 1), blk, 0, stream>>>(QKb, VTb, AOb);
  // 3) output projection (bf16 A, f32 weights, F32 OUTPUT)
  gemm_bt_kernel<false, true, true><<<dim3(6, 64, 1), blk, 0, stream>>>(
      AOb, Wproj, out, (unsigned short*)nullptr, 768, 768, 0);
}